// Round 1
// baseline (410.400 us; speedup 1.0000x reference)
//
#include <hip/hip_runtime.h>
#include <stdint.h>

// Problem constants: B=8, H=W=64, C=256
#define NB    8
#define NTOK  4096          // H*W tokens per batch
#define TOK   32768         // NB*NTOK
#define CDIM  256

// ---- split-K flash geometry ----
#define BQ2   128           // q rows per flash block (4 waves x 32)
#define BK2   32            // keys per LDS tile
#define NTB   128           // key tiles per batch (4096/32)
#define NT2   64            // tiles per block (half the keys)

#define KP2   272           // K tile row pitch in shorts (pad +16, 17408 B tile)
#define VP2   32            // Vt tile row pitch in shorts (no pad, 16384 B tile)
#define PLP   36            // P LDS pitch in shorts
#define KTILE2_SH (BK2 * KP2)    // 8704 shorts = 17408 B
#define VTILE2_SH (CDIM * VP2)   // 8192 shorts = 16384 B
#define KCH2  17            // 1-KB DMA chunks per K tile
#define VCH2  16            // 1-KB DMA chunks per V tile
#define TOTCH2 (KCH2 + VCH2) // 33

typedef __attribute__((ext_vector_type(8))) short bf16x8;   // 8 bf16 = 4 VGPRs
typedef __attribute__((ext_vector_type(4))) float f32x4;    // MFMA C/D frag

#define SSCALE 0.09016844f   // C^-0.5 * log2(e) = 0.0625 * 1.442695

static __device__ __forceinline__ unsigned short f2bf(float f) {
    union { float f; unsigned u; } v; v.f = f;
    unsigned r = v.u + 0x7fffu + ((v.u >> 16) & 1u);   // RNE
    return (unsigned short)(r >> 16);
}

// async global->LDS DMA: 16 B/lane, LDS dest = uniform base + lane*16
static __device__ __forceinline__ void dma16(const unsigned short* g, unsigned short* l) {
    __builtin_amdgcn_global_load_lds(
        (const __attribute__((address_space(1))) unsigned int*)g,
        (__attribute__((address_space(3))) unsigned int*)l,
        16, 0, 0);
}

// ---------------- prep: LayerNorm (blocks 0..8191) + weight transpose -------
__global__ __launch_bounds__(256) void prep_kernel(
        const float* __restrict__ x,
        const float* __restrict__ gamma,
        const float* __restrict__ beta,
        const float* __restrict__ w0, const float* __restrict__ w1,
        const float* __restrict__ w2, const float* __restrict__ w3,
        unsigned short* __restrict__ h_bf,
        unsigned short* __restrict__ wt) {
    int bx = blockIdx.x;
    if (bx >= TOK / 4) {
        // weight transpose + bf16 cast: Wt[d][c] = W[c][d]
        int id = bx - TOK / 4;            // 0..1023
        int m = id >> 8, dd = id & 255;
        const float* src = (m == 0) ? w0 : (m == 1) ? w1 : (m == 2) ? w2 : w3;
        wt[m * (CDIM * CDIM) + dd * CDIM + threadIdx.x] = f2bf(src[threadIdx.x * CDIM + dd]);
        return;
    }
    int w = threadIdx.x >> 6;
    int lane = threadIdx.x & 63;
    int token = bx * 4 + w;
    const float4 xv = ((const float4*)(x + (size_t)token * CDIM))[lane];
    float s = xv.x + xv.y + xv.z + xv.w;
    #pragma unroll
    for (int off = 1; off < 64; off <<= 1) s += __shfl_xor(s, off, 64);
    float mean = s * (1.0f / 256.0f);
    float d0 = xv.x - mean, d1 = xv.y - mean, d2 = xv.z - mean, d3 = xv.w - mean;
    float ss = d0 * d0 + d1 * d1 + d2 * d2 + d3 * d3;
    #pragma unroll
    for (int off = 1; off < 64; off <<= 1) ss += __shfl_xor(ss, off, 64);
    float rstd = rsqrtf(ss * (1.0f / 256.0f) + 1e-5f);
    float4 g = ((const float4*)gamma)[lane];
    float4 b = ((const float4*)beta)[lane];
    ushort4 o;
    o.x = f2bf(d0 * rstd * g.x + b.x);
    o.y = f2bf(d1 * rstd * g.y + b.y);
    o.z = f2bf(d2 * rstd * g.z + b.z);
    o.w = f2bf(d3 * rstd * g.w + b.w);
    ((ushort4*)(h_bf + (size_t)token * CDIM))[lane] = o;
}

// ---------------- fused Q+K+V projection, 4-way column-split ----------------
// grid (512, 4), 128 thr. Block (bx,gy) = token block bx (64 tokens), output
// columns nt = gy*4 .. gy*4+3 of ALL THREE projections. K and Vt now written
// as 32-key tiles (tile index = global_token/32) for the split-K flash.
__global__ __launch_bounds__(128) void qkv_kernel(
        const unsigned short* __restrict__ h_bf,
        const unsigned short* __restrict__ wts,
        const float* __restrict__ bq,
        const float* __restrict__ bk,
        const float* __restrict__ bv,
        unsigned short* __restrict__ q_bf,
        unsigned short* __restrict__ k2,
        unsigned short* __restrict__ vt2) {
    __shared__ unsigned short VT[64][72];   // 9216 B (quarter tile: d in [gy*64, gy*64+64))
    int tid = threadIdx.x;
    int w = tid >> 6, lane = tid & 63, quad = lane >> 4, l16 = lane & 15;
    int blk = blockIdx.x;
    int gy = blockIdx.y;
    int nt0 = gy * 4;
    int tok_base = blk * 64 + w * 32;

    bf16x8 afr[2][8];
    #pragma unroll
    for (int s = 0; s < 2; ++s)
        #pragma unroll
        for (int kk = 0; kk < 8; ++kk)
            afr[s][kk] = *(const bf16x8*)(h_bf + (size_t)(tok_base + s * 16 + l16) * CDIM + kk * 32 + quad * 8);

    // ---- Q (pre-scaled by SSCALE)
    {
        const unsigned short* wq_t = wts;
        #pragma unroll
        for (int ntl = 0; ntl < 4; ++ntl) {
            int nt = nt0 + ntl;
            f32x4 acc0 = {0.f, 0.f, 0.f, 0.f};
            f32x4 acc1 = {0.f, 0.f, 0.f, 0.f};
            #pragma unroll
            for (int kk = 0; kk < 8; ++kk) {
                bf16x8 bfr = *(const bf16x8*)(wq_t + (size_t)(nt * 16 + l16) * CDIM + kk * 32 + quad * 8);
                acc0 = __builtin_amdgcn_mfma_f32_16x16x32_bf16(afr[0][kk], bfr, acc0, 0, 0, 0);
                acc1 = __builtin_amdgcn_mfma_f32_16x16x32_bf16(afr[1][kk], bfr, acc1, 0, 0, 0);
            }
            int d = nt * 16 + l16;
            float bb = bq[d];
            #pragma unroll
            for (int r = 0; r < 4; ++r) {
                q_bf[(size_t)(tok_base + quad * 4 + r) * CDIM + d]      = f2bf((acc0[r] + bb) * SSCALE);
                q_bf[(size_t)(tok_base + 16 + quad * 4 + r) * CDIM + d] = f2bf((acc1[r] + bb) * SSCALE);
            }
        }
    }
    // ---- K (into padded 32-key tiles: tile = blk*2 + w)
    {
        const unsigned short* wk_t = wts + CDIM * CDIM;
        unsigned short* kdst = k2 + (size_t)(blk * 2 + w) * KTILE2_SH;
        #pragma unroll
        for (int ntl = 0; ntl < 4; ++ntl) {
            int nt = nt0 + ntl;
            f32x4 acc0 = {0.f, 0.f, 0.f, 0.f};
            f32x4 acc1 = {0.f, 0.f, 0.f, 0.f};
            #pragma unroll
            for (int kk = 0; kk < 8; ++kk) {
                bf16x8 bfr = *(const bf16x8*)(wk_t + (size_t)(nt * 16 + l16) * CDIM + kk * 32 + quad * 8);
                acc0 = __builtin_amdgcn_mfma_f32_16x16x32_bf16(afr[0][kk], bfr, acc0, 0, 0, 0);
                acc1 = __builtin_amdgcn_mfma_f32_16x16x32_bf16(afr[1][kk], bfr, acc1, 0, 0, 0);
            }
            int d = nt * 16 + l16;
            float bb = bk[d];
            #pragma unroll
            for (int r = 0; r < 4; ++r) {
                kdst[(size_t)(quad * 4 + r) * KP2 + d]      = f2bf(acc0[r] + bb);
                kdst[(size_t)(quad * 4 + 16 + r) * KP2 + d] = f2bf(acc1[r] + bb);
            }
        }
    }
    // ---- V (transpose through quarter-height LDS into 32-key tiles)
    {
        const unsigned short* wv_t = wts + 2 * CDIM * CDIM;
        int col0 = w * 32 + quad * 4;
        #pragma unroll
        for (int ntl = 0; ntl < 4; ++ntl) {
            int nt = nt0 + ntl;
            f32x4 acc0 = {0.f, 0.f, 0.f, 0.f};
            f32x4 acc1 = {0.f, 0.f, 0.f, 0.f};
            #pragma unroll
            for (int kk = 0; kk < 8; ++kk) {
                bf16x8 bfr = *(const bf16x8*)(wv_t + (size_t)(nt * 16 + l16) * CDIM + kk * 32 + quad * 8);
                acc0 = __builtin_amdgcn_mfma_f32_16x16x32_bf16(afr[0][kk], bfr, acc0, 0, 0, 0);
                acc1 = __builtin_amdgcn_mfma_f32_16x16x32_bf16(afr[1][kk], bfr, acc1, 0, 0, 0);
            }
            int d = nt * 16 + l16;
            float bb = bv[d];
            int dl = ntl * 16 + l16;          // local row (d - gy*64)
            #pragma unroll
            for (int r = 0; r < 4; ++r) {
                VT[dl][col0 + r]      = f2bf(acc0[r] + bb);
                VT[dl][col0 + 16 + r] = f2bf(acc1[r] + bb);
            }
        }
    }
    __syncthreads();
    // copy-out: two 32-key half tiles, 64 rows x 64 B each = 512 uint4
    #pragma unroll
    for (int j = 0; j < 4; ++j) {
        int idx = j * 128 + tid;          // 0..511
        int half = idx >> 8;              // 0/1
        int rem = idx & 255;
        int rr = rem >> 2;                // 0..63 local d row
        int c4 = rem & 3;                 // 16-B column chunk
        const uint4* src = (const uint4*)(&VT[rr][half * 32 + c4 * 8]);
        uint4* dst = (uint4*)(vt2 + (size_t)(blk * 2 + half) * VTILE2_SH
                                   + (size_t)(gy * 64 + rr) * VP2 + c4 * 8);
        *dst = *src;
    }
}

// ---------------- Flash attention: split-K, 2 independent blocks per CU -----
// 256 thr / 4 waves, BQ2=128 (wave w owns q-rows w*32..+32, full 32-key tile),
// each block covers HALF the keys (kh2*2048..+2048, 64 BK2=32 tiles).
// LDS = 76.8 KB -> 2 blocks/CU: two independent barrier domains per CU so one
// block's MFMA phase overlaps the other's softmax/DMA phase (the old 8-wave
// single-domain design was phase-locked: MfmaUtil 30%, VALUBusy 34%).
// Per-wave reuse geometry unchanged: every K/V frag feeds 2 MFMAs; O=128 regs.
// Blocks write UNNORMALIZED partial O + l; combine_kernel merges the halves.
#define DMA2(KS, VS, tl)                                                             \
    {                                                                                \
        const unsigned short* gk = k2 + (size_t)(tg0 + (tl)) * KTILE2_SH;            \
        const unsigned short* gv = vt2 + (size_t)(tg0 + (tl)) * VTILE2_SH;           \
        _Pragma("unroll")                                                            \
        for (int i = 0; i < 9; ++i) {                                                \
            int c = w + i * 4;                                                       \
            if (c < TOTCH2) {                                                        \
                if (c < KCH2) dma16(gk + c * 512 + lane * 8, &KS[0][0] + c * 512);   \
                else dma16(gv + (c - KCH2) * 512 + lane * 8, &VS[0][0] + (c - KCH2) * 512); \
            }                                                                        \
        }                                                                            \
    }

#define COMPUTE2(KS, VS)                                                             \
    {                                                                                \
        f32x4 sfr[2][2];                                                             \
        __builtin_amdgcn_s_setprio(1);                                               \
        _Pragma("unroll")                                                            \
        for (int nt = 0; nt < 2; ++nt) {                                             \
            f32x4 a0 = {0.f, 0.f, 0.f, 0.f};                                         \
            f32x4 a1 = {0.f, 0.f, 0.f, 0.f};                                         \
            _Pragma("unroll")                                                        \
            for (int kk = 0; kk < 8; ++kk) {                                         \
                bf16x8 kb = *(const bf16x8*)(&KS[nt * 16 + l16][kk * 32 + quad * 8]); \
                a0 = __builtin_amdgcn_mfma_f32_16x16x32_bf16(qfr[0][kk], kb, a0, 0, 0, 0); \
                a1 = __builtin_amdgcn_mfma_f32_16x16x32_bf16(qfr[1][kk], kb, a1, 0, 0, 0); \
            }                                                                        \
            sfr[0][nt] = a0; sfr[1][nt] = a1;                                        \
        }                                                                            \
        __builtin_amdgcn_s_setprio(0);                                               \
        _Pragma("unroll")                                                            \
        for (int s = 0; s < 2; ++s)                                                  \
            _Pragma("unroll")                                                        \
            for (int nt = 0; nt < 2; ++nt)                                           \
                _Pragma("unroll")                                                    \
                for (int r = 0; r < 4; ++r) {                                        \
                    float p = __builtin_amdgcn_exp2f(sfr[s][nt][r]);                 \
                    lacc[s][r] += p;                                                 \
                    Pl[w * 32 + s * 16 + quad * 4 + r][nt * 16 + l16] = f2bf(p);     \
                }                                                                    \
        bf16x8 pfr0 = *(const bf16x8*)(&Pl[w * 32 + l16][quad * 8]);                 \
        bf16x8 pfr1 = *(const bf16x8*)(&Pl[w * 32 + 16 + l16][quad * 8]);            \
        __builtin_amdgcn_s_setprio(1);                                               \
        _Pragma("unroll")                                                            \
        for (int nt2 = 0; nt2 < 16; ++nt2) {                                         \
            bf16x8 vb = *(const bf16x8*)(&VS[nt2 * 16 + l16][quad * 8]);             \
            O[0][nt2] = __builtin_amdgcn_mfma_f32_16x16x32_bf16(pfr0, vb, O[0][nt2], 0, 0, 0); \
            O[1][nt2] = __builtin_amdgcn_mfma_f32_16x16x32_bf16(pfr1, vb, O[1][nt2], 0, 0, 0); \
        }                                                                            \
        __builtin_amdgcn_s_setprio(0);                                               \
    }

__global__ __launch_bounds__(256, 2) void flash_kernel(
        const unsigned short* __restrict__ q_bf,
        const unsigned short* __restrict__ k2,
        const unsigned short* __restrict__ vt2,
        unsigned short* __restrict__ attn1,   // bf16 partial, key-half 1 (h region)
        float* __restrict__ attn0,            // f32 partial, key-half 0 (d_out as scratch)
        float* __restrict__ lws) {            // [2][TOK] partial softmax denominators
    __shared__ unsigned short Ks0[BK2][KP2];    // 17408 B
    __shared__ unsigned short Ks1[BK2][KP2];    // 17408 B
    __shared__ unsigned short Vs0[CDIM][VP2];   // 16384 B
    __shared__ unsigned short Vs1[CDIM][VP2];   // 16384 B
    __shared__ unsigned short Pl[BQ2][PLP];     // 9216 B   (total 76800 B)

    int tid = threadIdx.x;
    int w = tid >> 6, lane = tid & 63, quad = lane >> 4, l16 = lane & 15;
    int bid = blockIdx.x;
    int b = bid & 7;                 // XCD swizzle: same batch -> same XCD L2
    int qtile = (bid >> 3) & 31;
    int kh2 = bid >> 8;              // key half (0/1)
    int qrow = qtile * BQ2 + w * 32;
    int rowb = b * NTOK + qrow;      // global token row base for this wave
    int tg0 = b * NTB + kh2 * NT2;   // global tile base in k2/vt2

    bf16x8 qfr[2][8];
    #pragma unroll
    for (int s = 0; s < 2; ++s)
        #pragma unroll
        for (int kk = 0; kk < 8; ++kk)
            qfr[s][kk] = *(const bf16x8*)(q_bf + (size_t)(rowb + s * 16 + l16) * CDIM + kk * 32 + quad * 8);

    f32x4 O[2][16];
    #pragma unroll
    for (int s = 0; s < 2; ++s)
        #pragma unroll
        for (int i = 0; i < 16; ++i) O[s][i] = (f32x4){0.f, 0.f, 0.f, 0.f};
    float lacc[2][4] = {{0.f, 0.f, 0.f, 0.f}, {0.f, 0.f, 0.f, 0.f}};

    DMA2(Ks0, Vs0, 0);
    __syncthreads();

    for (int kt2 = 0; kt2 < NT2; kt2 += 2) {
        DMA2(Ks1, Vs1, kt2 + 1);
        COMPUTE2(Ks0, Vs0);
        __syncthreads();
        if (kt2 + 2 < NT2) DMA2(Ks0, Vs0, kt2 + 2);
        COMPUTE2(Ks1, Vs1);
        __syncthreads();
    }

    // ---- epilogue: per-wave, no cross-wave combine. Reduce l over key cols.
    float lred[2][4];
    #pragma unroll
    for (int s = 0; s < 2; ++s)
        #pragma unroll
        for (int r = 0; r < 4; ++r) {
            float ls = lacc[s][r];
            #pragma unroll
            for (int off = 1; off < 16; off <<= 1) ls += __shfl_xor(ls, off, 64);
            lred[s][r] = ls;
        }
    if (l16 == 0) {
        #pragma unroll
        for (int s = 0; s < 2; ++s)
            #pragma unroll
            for (int r = 0; r < 4; ++r)
                lws[kh2 * TOK + rowb + s * 16 + quad * 4 + r] = lred[s][r];
    }
    if (kh2 == 0) {
        #pragma unroll
        for (int s = 0; s < 2; ++s)
            #pragma unroll
            for (int nt2 = 0; nt2 < 16; ++nt2)
                #pragma unroll
                for (int r = 0; r < 4; ++r)
                    attn0[(size_t)(rowb + s * 16 + quad * 4 + r) * CDIM + nt2 * 16 + l16] = O[s][nt2][r];
    } else {
        #pragma unroll
        for (int s = 0; s < 2; ++s)
            #pragma unroll
            for (int nt2 = 0; nt2 < 16; ++nt2)
                #pragma unroll
                for (int r = 0; r < 4; ++r)
                    attn1[(size_t)(rowb + s * 16 + quad * 4 + r) * CDIM + nt2 * 16 + l16] = f2bf(O[s][nt2][r]);
    }
}

// ---------------- combine the two key-half partials -> final attn bf16 ------
// attn = (O0 + O1) / (l0 + l1), written in place over the bf16 partial (h reg).
__global__ __launch_bounds__(256) void combine_kernel(
        const float* __restrict__ p0,          // f32 partial (d_out scratch)
        unsigned short* __restrict__ p1,       // bf16 partial -> final attn (in place)
        const float* __restrict__ lws) {
    int t = blockIdx.x * 256 + threadIdx.x;    // 0 .. TOK*32-1, 8 channels each
    int row = t >> 5;
    int c8 = (t & 31) * 8;
    float inv = 1.0f / (lws[row] + lws[TOK + row]);
    const float4* a = (const float4*)(p0 + (size_t)row * CDIM + c8);
    float4 x0 = a[0], x1 = a[1];
    uint4 bv = *(const uint4*)(p1 + (size_t)row * CDIM + c8);
    float f0 = __uint_as_float((bv.x & 0xffffu) << 16);
    float f1 = __uint_as_float(bv.x & 0xffff0000u);
    float f2 = __uint_as_float((bv.y & 0xffffu) << 16);
    float f3 = __uint_as_float(bv.y & 0xffff0000u);
    float f4 = __uint_as_float((bv.z & 0xffffu) << 16);
    float f5 = __uint_as_float(bv.z & 0xffff0000u);
    float f6 = __uint_as_float((bv.w & 0xffffu) << 16);
    float f7 = __uint_as_float(bv.w & 0xffff0000u);
    float v0 = (x0.x + f0) * inv, v1 = (x0.y + f1) * inv;
    float v2 = (x0.z + f2) * inv, v3 = (x0.w + f3) * inv;
    float v4 = (x1.x + f4) * inv, v5 = (x1.y + f5) * inv;
    float v6 = (x1.z + f6) * inv, v7 = (x1.w + f7) * inv;
    uint4 o;
    o.x = (unsigned)f2bf(v0) | ((unsigned)f2bf(v1) << 16);
    o.y = (unsigned)f2bf(v2) | ((unsigned)f2bf(v3) << 16);
    o.z = (unsigned)f2bf(v4) | ((unsigned)f2bf(v5) << 16);
    o.w = (unsigned)f2bf(v6) | ((unsigned)f2bf(v7) << 16);
    *(uint4*)(p1 + (size_t)row * CDIM + c8) = o;
}

// ---------------- output projection + bias + residual, 2-way column-split ---
__global__ __launch_bounds__(128) void oproj_kernel(
        const unsigned short* __restrict__ attn,
        const unsigned short* __restrict__ wo_t,
        const float* __restrict__ bo,
        const float* __restrict__ x,
        float* __restrict__ out) {
    int w = threadIdx.x >> 6, lane = threadIdx.x & 63;
    int quad = lane >> 4, l16 = lane & 15;
    int tok_base = blockIdx.x * 64 + w * 32;
    int nt0 = blockIdx.y * 8;

    bf16x8 afr[2][8];
    #pragma unroll
    for (int s = 0; s < 2; ++s)
        #pragma unroll
        for (int kk = 0; kk < 8; ++kk)
            afr[s][kk] = *(const bf16x8*)(attn + (size_t)(tok_base + s * 16 + l16) * CDIM + kk * 32 + quad * 8);

    #pragma unroll
    for (int ntl = 0; ntl < 8; ++ntl) {
        int nt = nt0 + ntl;
        f32x4 acc0 = {0.f, 0.f, 0.f, 0.f};
        f32x4 acc1 = {0.f, 0.f, 0.f, 0.f};
        #pragma unroll
        for (int kk = 0; kk < 8; ++kk) {
            bf16x8 bfr = *(const bf16x8*)(wo_t + (size_t)(nt * 16 + l16) * CDIM + kk * 32 + quad * 8);
            acc0 = __builtin_amdgcn_mfma_f32_16x16x32_bf16(afr[0][kk], bfr, acc0, 0, 0, 0);
            acc1 = __builtin_amdgcn_mfma_f32_16x16x32_bf16(afr[1][kk], bfr, acc1, 0, 0, 0);
        }
        int d = nt * 16 + l16;
        float bb = bo[d];
        #pragma unroll
        for (int r = 0; r < 4; ++r) {
            size_t idx0 = (size_t)(tok_base + quad * 4 + r) * CDIM + d;
            size_t idx1 = (size_t)(tok_base + 16 + quad * 4 + r) * CDIM + d;
            out[idx0] = x[idx0] + acc0[r] + bb;
            out[idx1] = x[idx1] + acc1[r] + bb;
        }
    }
}

extern "C" void kernel_launch(void* const* d_in, const int* in_sizes, int n_in,
                              void* d_out, int out_size, void* d_ws, size_t ws_size,
                              hipStream_t stream) {
    const float* x     = (const float*)d_in[0];
    const float* gamma = (const float*)d_in[1];
    const float* beta  = (const float*)d_in[2];
    const float* wq    = (const float*)d_in[3];
    const float* bq    = (const float*)d_in[4];
    const float* wk    = (const float*)d_in[5];
    const float* bk    = (const float*)d_in[6];
    const float* wv    = (const float*)d_in[7];
    const float* bv    = (const float*)d_in[8];
    const float* wo    = (const float*)d_in[9];
    const float* bo    = (const float*)d_in[10];
    float* out = (float*)d_out;

    // workspace layout (bytes):
    //   h    @ 0          16,777,216   (LN output; reused as bf16 partial-1 / final attn)
    //   q    @ 16,777,216 16,777,216
    //   k2   @ 33,554,432 17,825,792   (1024 tiles x 32 x 272 bf16)
    //   vt2  @ 51,380,224 16,777,216   (1024 tiles x 256 x 32 bf16)
    //   wt   @ 68,157,440    524,288   (4 transposed bf16 weight matrices)
    //   lws  @ 68,681,728    262,144   ([2][32768] f32 partial denominators)
    // f32 partial-0 lives in d_out (scratch until oproj overwrites it).
    char* ws = (char*)d_ws;
    unsigned short* h_bf = (unsigned short*)(ws);
    unsigned short* q_bf = (unsigned short*)(ws + 16777216);
    unsigned short* k2   = (unsigned short*)(ws + 33554432);
    unsigned short* vt2  = (unsigned short*)(ws + 51380224);
    unsigned short* wt   = (unsigned short*)(ws + 68157440);
    float* lws           = (float*)(ws + 68681728);
    unsigned short* attn = h_bf;   // h dead after qkv

    prep_kernel<<<TOK / 4 + 1024, 256, 0, stream>>>(x, gamma, beta, wq, wk, wv, wo, h_bf, wt);
    qkv_kernel<<<dim3(TOK / 64, 4), 128, 0, stream>>>(h_bf, wt, bq, bk, bv, q_bf, k2, vt2);
    flash_kernel<<<512, 256, 0, stream>>>(q_bf, k2, vt2, attn, out, lws);
    combine_kernel<<<TOK * 32 / 256, 256, 0, stream>>>(out, attn, lws);
    oproj_kernel<<<dim3(TOK / 64, 2), 128, 0, stream>>>(attn, wt + 3 * (CDIM * CDIM), bo, x, out);
}